// Round 7
// baseline (13397.427 us; speedup 1.0000x reference)
//
#include <hip/hip_runtime.h>

// LSTM: S=4096, I=64, H=1024, O=1, fp32.
// Persistent cooperative kernel, 128 blocks x 576 threads (9 waves).
//   wave 0: dedicated poller/broadcaster (polls global tagged slots, stages
//           h into LDS, release-stores tagged hready flag).
//   waves 1..8: compute one h each (4 gate rows, 16 lanes/row); spin on the
//           LDS hready flag (~130cy wake, no L3 poll); publish OWN tagged 8B
//           word directly into the block's 64B line (no gather hop).
// ZERO __syncthreads in the step loop. Safety: tag s+2 can only appear after
// its producer read all s+1 slots (incl. ours) => our computers finished
// reading hs[s&1] => poller may overwrite it.
// Protocol (rounds 5-6, validated): {tag:32|h_bits:32} relaxed agent-scope
// atomics, tagged double buffer, zero fences.

#define SEQ_LEN 4096
#define HID 1024
#define NBLK 128
#define TPB 576
#define HPB 8      // h-indices per block (one per computing wave)

__device__ __forceinline__ float fast_sigmoid(float x) {
    return __builtin_amdgcn_rcpf(1.0f + __builtin_amdgcn_exp2f(-1.4426950408889634f * x));
}
__device__ __forceinline__ float fast_tanh(float x) {
    return fmaf(-2.0f, __builtin_amdgcn_rcpf(1.0f + __builtin_amdgcn_exp2f(2.8853900817779268f * x)), 1.0f);
}

// ws: unsigned long long slots[2][1024]. {tag<<32 | fp32 bits}. Zero-init:
// buffer0 tag0/val0 == h_0 = 0 (correct); buffer1 receives odd tags.
__global__ void lstm_init_kernel(unsigned long long* ws) {
    int t = threadIdx.x;
    #pragma unroll
    for (int k = 0; k < 8; ++k) ws[t + 256 * k] = 0ull;
}

__global__ __launch_bounds__(TPB, 1) void lstm_persistent_kernel(
    const float* __restrict__ input,   // [4096][64]
    const float* __restrict__ W_ih,    // [4096][64]
    const float* __restrict__ W_hh,    // [4096][1024]
    const float* __restrict__ b_ih,    // [4096]
    const float* __restrict__ b_hh,    // [4096]
    const float* __restrict__ W_lin,   // [1][1024]
    const float* __restrict__ b_lin,   // [1]
    float* __restrict__ out,           // [1]
    unsigned long long* __restrict__ ws)
{
    const int t = threadIdx.x;
    const int b = blockIdx.x;
    const int w = t >> 6;        // wave 0 = poller; 1..8 compute
    const int l = t & 63;

    unsigned long long* slot0 = ws;          // even tags
    unsigned long long* slot1 = ws + HID;    // odd tags

    __shared__ float4 wlds4[17 * 512];       // 136 KB weight slice (computing threads)
    __shared__ float  hs[2][HID];            // double-buffered h (8 KB)
    __shared__ unsigned hready[2];           // tagged ready flags per parity

    // ---- init staging (all waves), ONE barrier total ----
    const int tc  = t - 64;                  // computing-thread index 0..511
    const int grp = l >> 4;                  // gate q (i,f,g,o)
    const int sl  = l & 15;                  // sub-lane within gate group
    const int j   = HPB * b + (w - 1);       // owned h index (computing waves)
    const int row = grp * HID + j;

    float bias[4];
    if (w > 0) {
        const float4* Whh4 = (const float4*)(W_hh + (size_t)row * HID);
        #pragma unroll
        for (int c = 0; c < 16; ++c)
            wlds4[c * 512 + tc] = Whh4[sl + 16 * c];    // W_hh[row][64c+4sl..+3]
        wlds4[16 * 512 + tc] = ((const float4*)(W_ih + (size_t)row * 64))[sl];
        #pragma unroll
        for (int q = 0; q < 4; ++q) bias[q] = b_ih[q * HID + j] + b_hh[q * HID + j];
    }
    if (t < 2) hready[t] = 0u;
    __syncthreads();

    if (w == 0) {
        // ================= poller / broadcaster wave =================
        for (int s = 0; s < SEQ_LEN; ++s) {
            unsigned long long* rs = (s & 1) ? slot1 : slot0;
            const unsigned tag = (unsigned)s;
            float* hsb = hs[s & 1];
            unsigned long long v[16];
            bool ok;
            do {
                #pragma unroll
                for (int k = 0; k < 16; ++k)
                    v[k] = __hip_atomic_load(&rs[l + 64 * k], __ATOMIC_RELAXED,
                                             __HIP_MEMORY_SCOPE_AGENT);
                ok = true;
                #pragma unroll
                for (int k = 0; k < 16; ++k)
                    ok = ok && ((unsigned)(v[k] >> 32) == tag);
            } while (!__all(ok));
            #pragma unroll
            for (int k = 0; k < 16; ++k)
                hsb[l + 64 * k] = __uint_as_float((unsigned)(v[k] & 0xffffffffull));
            if (l == 0)
                __hip_atomic_store(&hready[s & 1], (unsigned)(s + 1),
                                   __ATOMIC_RELEASE, __HIP_MEMORY_SCOPE_WORKGROUP);
        }
        // ---- final projection: block 0 poller dots h_4096 with W_lin ----
        if (b == 0) {
            const unsigned tag = (unsigned)SEQ_LEN;   // even -> slot0
            unsigned long long v[16];
            bool ok;
            do {
                #pragma unroll
                for (int k = 0; k < 16; ++k)
                    v[k] = __hip_atomic_load(&slot0[l + 64 * k], __ATOMIC_RELAXED,
                                             __HIP_MEMORY_SCOPE_AGENT);
                ok = true;
                #pragma unroll
                for (int k = 0; k < 16; ++k)
                    ok = ok && ((unsigned)(v[k] >> 32) == tag);
            } while (!__all(ok));
            float p = 0.0f;
            #pragma unroll
            for (int k = 0; k < 16; ++k)
                p = fmaf(__uint_as_float((unsigned)(v[k] & 0xffffffffull)),
                         W_lin[l + 64 * k], p);
            #pragma unroll
            for (int m = 32; m >= 1; m >>= 1) p += __shfl_xor(p, m);
            if (l == 0) out[0] = p + b_lin[0];
        }
    } else {
        // ================= computing waves =================
        const float4* xin4 = (const float4*)input;
        float c_state = 0.0f;
        for (int s = 0; s < SEQ_LEN; ++s) {
            float4 x4 = xin4[s * 16 + sl];   // issue before spin (cacheable)

            // wait for poller to stage h_s (LDS spin, ~130cy wake)
            const unsigned need = (unsigned)(s + 1);
            while (__hip_atomic_load(&hready[s & 1], __ATOMIC_ACQUIRE,
                                     __HIP_MEMORY_SCOPE_WORKGROUP) < need) {}

            // ---- 68 FMAs, 4 split accumulators ----
            const float4* hs4 = (const float4*)hs[s & 1];
            float a0 = 0.f, a1 = 0.f, a2 = 0.f, a3 = 0.f;
            #pragma unroll
            for (int c = 0; c < 16; c += 4) {
                float4 wv0 = wlds4[(c    ) * 512 + tc], h40 = hs4[16 * (c    ) + sl];
                float4 wv1 = wlds4[(c + 1) * 512 + tc], h41 = hs4[16 * (c + 1) + sl];
                float4 wv2 = wlds4[(c + 2) * 512 + tc], h42 = hs4[16 * (c + 2) + sl];
                float4 wv3 = wlds4[(c + 3) * 512 + tc], h43 = hs4[16 * (c + 3) + sl];
                a0 = fmaf(wv0.x, h40.x, a0); a0 = fmaf(wv0.y, h40.y, a0);
                a0 = fmaf(wv0.z, h40.z, a0); a0 = fmaf(wv0.w, h40.w, a0);
                a1 = fmaf(wv1.x, h41.x, a1); a1 = fmaf(wv1.y, h41.y, a1);
                a1 = fmaf(wv1.z, h41.z, a1); a1 = fmaf(wv1.w, h41.w, a1);
                a2 = fmaf(wv2.x, h42.x, a2); a2 = fmaf(wv2.y, h42.y, a2);
                a2 = fmaf(wv2.z, h42.z, a2); a2 = fmaf(wv2.w, h42.w, a2);
                a3 = fmaf(wv3.x, h43.x, a3); a3 = fmaf(wv3.y, h43.y, a3);
                a3 = fmaf(wv3.z, h43.z, a3); a3 = fmaf(wv3.w, h43.w, a3);
            }
            {
                float4 wv = wlds4[16 * 512 + tc];
                a0 = fmaf(wv.x, x4.x, a0); a1 = fmaf(wv.y, x4.y, a1);
                a2 = fmaf(wv.z, x4.z, a2); a3 = fmaf(wv.w, x4.w, a3);
            }
            float acc = (a0 + a1) + (a2 + a3);

            // reduce across 16 lanes of the gate group
            acc += __shfl_xor(acc, 1);
            acc += __shfl_xor(acc, 2);
            acc += __shfl_xor(acc, 4);
            acc += __shfl_xor(acc, 8);

            float gi = __shfl(acc, 0)  + bias[0];
            float gf = __shfl(acc, 16) + bias[1];
            float gg = __shfl(acc, 32) + bias[2];
            float go = __shfl(acc, 48) + bias[3];

            float ig = fast_sigmoid(gi);
            float fg = fast_sigmoid(gf);
            float cg = fast_tanh(gg);
            float og = fast_sigmoid(go);
            c_state  = fmaf(fg, c_state, ig * cg);
            float hn = og * fast_tanh(c_state);

            // ---- publish own tagged word directly (8B into block's 64B line) ----
            if (l == 0) {
                unsigned long long pv = ((unsigned long long)need << 32) |
                                        (unsigned long long)__float_as_uint(hn);
                unsigned long long* wsl = (s & 1) ? slot0 : slot1;   // buffer (s+1)&1
                __hip_atomic_store(&wsl[j], pv, __ATOMIC_RELAXED,
                                   __HIP_MEMORY_SCOPE_AGENT);
            }
        }
    }
}

extern "C" void kernel_launch(void* const* d_in, const int* in_sizes, int n_in,
                              void* d_out, int out_size, void* d_ws, size_t ws_size,
                              hipStream_t stream) {
    const float* input = (const float*)d_in[0];
    const float* W_ih  = (const float*)d_in[1];
    const float* W_hh  = (const float*)d_in[2];
    const float* b_ih  = (const float*)d_in[3];
    const float* b_hh  = (const float*)d_in[4];
    const float* W_lin = (const float*)d_in[5];
    const float* b_lin = (const float*)d_in[6];
    float* out = (float*)d_out;
    unsigned long long* ws = (unsigned long long*)d_ws;

    hipLaunchKernelGGL(lstm_init_kernel, dim3(1), dim3(256), 0, stream, ws);

    void* args[] = { (void*)&input, (void*)&W_ih, (void*)&W_hh, (void*)&b_ih,
                     (void*)&b_hh, (void*)&W_lin, (void*)&b_lin, (void*)&out, (void*)&ws };
    (void)hipLaunchCooperativeKernel((void*)lstm_persistent_kernel, dim3(NBLK), dim3(TPB),
                                     args, 0, stream);
}

// Round 8
// 8805.853 us; speedup vs baseline: 1.5214x; 1.5214x over previous
//
#include <hip/hip_runtime.h>

// LSTM: S=4096, I=64, H=1024, O=1, fp32.
// Persistent cooperative kernel, 128 blocks x 576 threads (9 waves).
// Round-8 structure = round 6 (best: 2.05us/step) + dedicated publisher wave:
//   waves 1..8: compute one h each; poll 2 global slots/thread, stage to LDS,
//               __syncthreads, 68 FMAs, post tagged result to LDS pub[].
//   wave 0:     publisher only — spins on pub[] (LDS, fast wake), issues the
//               coalesced 64B line publish the moment the last wave posts.
//               Participates in the per-step barrier (counts match; publish
//               precedes its barrier arrival -> no deadlock).
// Protocol (rounds 5-6, validated): tagged 8-byte slots {tag:32|h_bits:32},
// relaxed agent-scope atomics, tagged double buffer, zero fences.
// Round-7 lesson: per-wave 8B publishes (1024 arrival events, WRITE_SIZE 4x)
// cost +1.2us/step — publish MUST stay one 64B line per block.

#define SEQ_LEN 4096
#define HID 1024
#define NBLK 128
#define TPB 576
#define HPB 8      // h-indices per block (one per computing wave)

__device__ __forceinline__ float fast_sigmoid(float x) {
    return __builtin_amdgcn_rcpf(1.0f + __builtin_amdgcn_exp2f(-1.4426950408889634f * x));
}
__device__ __forceinline__ float fast_tanh(float x) {
    return fmaf(-2.0f, __builtin_amdgcn_rcpf(1.0f + __builtin_amdgcn_exp2f(2.8853900817779268f * x)), 1.0f);
}

// ws: unsigned long long slots[2][1024]. {tag<<32 | fp32 bits}. Zero-init:
// buffer0 tag0/val0 == h_0 = 0 (correct); buffer1 receives odd tags.
__global__ void lstm_init_kernel(unsigned long long* ws) {
    int t = threadIdx.x;
    #pragma unroll
    for (int k = 0; k < 8; ++k) ws[t + 256 * k] = 0ull;
}

__global__ __launch_bounds__(TPB, 1) void lstm_persistent_kernel(
    const float* __restrict__ input,   // [4096][64]
    const float* __restrict__ W_ih,    // [4096][64]
    const float* __restrict__ W_hh,    // [4096][1024]
    const float* __restrict__ b_ih,    // [4096]
    const float* __restrict__ b_hh,    // [4096]
    const float* __restrict__ W_lin,   // [1][1024]
    const float* __restrict__ b_lin,   // [1]
    float* __restrict__ out,           // [1]
    unsigned long long* __restrict__ ws)
{
    const int t = threadIdx.x;
    const int b = blockIdx.x;
    const int w = t >> 6;        // wave 0 = publisher; 1..8 compute
    const int l = t & 63;

    unsigned long long* slot0 = ws;          // even tags
    unsigned long long* slot1 = ws + HID;    // odd tags

    __shared__ float4 wlds4[17 * 512];       // 136 KB weight slice
    __shared__ float  hs[2][HID];            // double-buffered h (8 KB)
    __shared__ unsigned long long pub[HPB];  // tagged intra-block handoff
    __shared__ float  red[16];

    const int tc  = t - 64;                  // computing-thread index 0..511
    const int grp = l >> 4;                  // gate q (i,f,g,o)
    const int sl  = l & 15;                  // sub-lane within gate group
    const int j   = HPB * b + (w - 1);       // owned h index (computing waves)
    const int row = grp * HID + j;

    float bias[4];
    if (w > 0) {
        const float4* Whh4 = (const float4*)(W_hh + (size_t)row * HID);
        #pragma unroll
        for (int c = 0; c < 16; ++c)
            wlds4[c * 512 + tc] = Whh4[sl + 16 * c];    // W_hh[row][64c+4sl..+3]
        wlds4[16 * 512 + tc] = ((const float4*)(W_ih + (size_t)row * 64))[sl];
        #pragma unroll
        for (int q = 0; q < 4; ++q) bias[q] = b_ih[q * HID + j] + b_hh[q * HID + j];
    }
    if (t < HPB) pub[t] = 0ull;
    __syncthreads();   // weights staged, pub initialized

    if (w == 0) {
        // ================= publisher wave =================
        asm volatile("s_setprio 1");   // fast wake from LDS spin
        for (int s = 0; s < SEQ_LEN; ++s) {
            __syncthreads();           // barrier A(s): h_s staged by computers
            // computers now compute h_{s+1} and post tagged words to pub[]
            const unsigned ntag = (unsigned)(s + 1);
            unsigned long long pv = 0;
            if (l < HPB) {
                do {
                    pv = __hip_atomic_load(&pub[l], __ATOMIC_RELAXED,
                                           __HIP_MEMORY_SCOPE_WORKGROUP);
                } while ((unsigned)(pv >> 32) != ntag);
                unsigned long long* wsl = (s & 1) ? slot0 : slot1;  // buffer (s+1)&1
                __hip_atomic_store(&wsl[HPB * b + l], pv, __ATOMIC_RELAXED,
                                   __HIP_MEMORY_SCOPE_AGENT);       // one 64B line
            }
        }
    } else {
        // ================= computing waves =================
        const float4* xin4 = (const float4*)input;
        float c_state = 0.0f;
        for (int s = 0; s < SEQ_LEN; ++s) {
            float4 x4 = xin4[s * 16 + sl];   // issue before poll (cacheable)

            // ---- poll 2 tagged slots (relaxed agent atomics, rd-flags) ----
            unsigned long long* rs = (s & 1) ? slot1 : slot0;
            const unsigned tag = (unsigned)s;
            unsigned long long v0, v1;
            bool r0 = false, r1 = false;
            do {
                if (!r0) { v0 = __hip_atomic_load(&rs[tc      ], __ATOMIC_RELAXED, __HIP_MEMORY_SCOPE_AGENT);
                           r0 = ((unsigned)(v0 >> 32) == tag); }
                if (!r1) { v1 = __hip_atomic_load(&rs[tc + 512], __ATOMIC_RELAXED, __HIP_MEMORY_SCOPE_AGENT);
                           r1 = ((unsigned)(v1 >> 32) == tag); }
            } while (!(r0 && r1));

            float* hsb = hs[s & 1];
            hsb[tc      ] = __uint_as_float((unsigned)(v0 & 0xffffffffull));
            hsb[tc + 512] = __uint_as_float((unsigned)(v1 & 0xffffffffull));

            __syncthreads();   // barrier A(s): full h_s staged (publisher joins)

            // ---- 68 FMAs, 4 split accumulators ----
            const float4* hs4 = (const float4*)hsb;
            float a0 = 0.f, a1 = 0.f, a2 = 0.f, a3 = 0.f;
            #pragma unroll
            for (int c = 0; c < 16; c += 4) {
                float4 wv0 = wlds4[(c    ) * 512 + tc], h40 = hs4[16 * (c    ) + sl];
                float4 wv1 = wlds4[(c + 1) * 512 + tc], h41 = hs4[16 * (c + 1) + sl];
                float4 wv2 = wlds4[(c + 2) * 512 + tc], h42 = hs4[16 * (c + 2) + sl];
                float4 wv3 = wlds4[(c + 3) * 512 + tc], h43 = hs4[16 * (c + 3) + sl];
                a0 = fmaf(wv0.x, h40.x, a0); a0 = fmaf(wv0.y, h40.y, a0);
                a0 = fmaf(wv0.z, h40.z, a0); a0 = fmaf(wv0.w, h40.w, a0);
                a1 = fmaf(wv1.x, h41.x, a1); a1 = fmaf(wv1.y, h41.y, a1);
                a1 = fmaf(wv1.z, h41.z, a1); a1 = fmaf(wv1.w, h41.w, a1);
                a2 = fmaf(wv2.x, h42.x, a2); a2 = fmaf(wv2.y, h42.y, a2);
                a2 = fmaf(wv2.z, h42.z, a2); a2 = fmaf(wv2.w, h42.w, a2);
                a3 = fmaf(wv3.x, h43.x, a3); a3 = fmaf(wv3.y, h43.y, a3);
                a3 = fmaf(wv3.z, h43.z, a3); a3 = fmaf(wv3.w, h43.w, a3);
            }
            {
                float4 wv = wlds4[16 * 512 + tc];
                a0 = fmaf(wv.x, x4.x, a0); a1 = fmaf(wv.y, x4.y, a1);
                a2 = fmaf(wv.z, x4.z, a2); a3 = fmaf(wv.w, x4.w, a3);
            }
            float acc = (a0 + a1) + (a2 + a3);

            // reduce across 16 lanes of the gate group
            acc += __shfl_xor(acc, 1);
            acc += __shfl_xor(acc, 2);
            acc += __shfl_xor(acc, 4);
            acc += __shfl_xor(acc, 8);

            float gi = __shfl(acc, 0)  + bias[0];
            float gf = __shfl(acc, 16) + bias[1];
            float gg = __shfl(acc, 32) + bias[2];
            float go = __shfl(acc, 48) + bias[3];

            float ig = fast_sigmoid(gi);
            float fg = fast_sigmoid(gf);
            float cg = fast_tanh(gg);
            float og = fast_sigmoid(go);
            c_state  = fmaf(fg, c_state, ig * cg);
            float hn = og * fast_tanh(c_state);

            // ---- post tagged word to publisher (LDS, no barrier) ----
            if (l == 0) {
                unsigned long long pv = ((unsigned long long)(unsigned)(s + 1) << 32) |
                                        (unsigned long long)__float_as_uint(hn);
                __hip_atomic_store(&pub[w - 1], pv, __ATOMIC_RELAXED,
                                   __HIP_MEMORY_SCOPE_WORKGROUP);
            }
        }
    }

    // ---- final projection (block 0, all 9 waves reach here) ----
    if (b == 0) {
        float p = 0.0f;
        if (w > 0) {
            const unsigned tag = (unsigned)SEQ_LEN;   // even -> slot0
            unsigned long long v0, v1;
            bool r0 = false, r1 = false;
            do {
                if (!r0) { v0 = __hip_atomic_load(&slot0[tc      ], __ATOMIC_RELAXED, __HIP_MEMORY_SCOPE_AGENT);
                           r0 = ((unsigned)(v0 >> 32) == tag); }
                if (!r1) { v1 = __hip_atomic_load(&slot0[tc + 512], __ATOMIC_RELAXED, __HIP_MEMORY_SCOPE_AGENT);
                           r1 = ((unsigned)(v1 >> 32) == tag); }
            } while (!(r0 && r1));
            p = __uint_as_float((unsigned)(v0 & 0xffffffffull)) * W_lin[tc] +
                __uint_as_float((unsigned)(v1 & 0xffffffffull)) * W_lin[tc + 512];
        }
        #pragma unroll
        for (int m = 32; m >= 1; m >>= 1) p += __shfl_xor(p, m);
        if (l == 0) red[w] = p;
        __syncthreads();
        if (t == 0) {
            float r = 0.f;
            #pragma unroll
            for (int k = 1; k <= HPB; ++k) r += red[k];
            out[0] = r + b_lin[0];
        }
    }
}

extern "C" void kernel_launch(void* const* d_in, const int* in_sizes, int n_in,
                              void* d_out, int out_size, void* d_ws, size_t ws_size,
                              hipStream_t stream) {
    const float* input = (const float*)d_in[0];
    const float* W_ih  = (const float*)d_in[1];
    const float* W_hh  = (const float*)d_in[2];
    const float* b_ih  = (const float*)d_in[3];
    const float* b_hh  = (const float*)d_in[4];
    const float* W_lin = (const float*)d_in[5];
    const float* b_lin = (const float*)d_in[6];
    float* out = (float*)d_out;
    unsigned long long* ws = (unsigned long long*)d_ws;

    hipLaunchKernelGGL(lstm_init_kernel, dim3(1), dim3(256), 0, stream, ws);

    void* args[] = { (void*)&input, (void*)&W_ih, (void*)&W_hh, (void*)&b_ih,
                     (void*)&b_hh, (void*)&W_lin, (void*)&b_lin, (void*)&out, (void*)&ws };
    (void)hipLaunchCooperativeKernel((void*)lstm_persistent_kernel, dim3(NBLK), dim3(TPB),
                                     args, 0, stream);
}

// Round 9
// 8294.286 us; speedup vs baseline: 1.6153x; 1.0617x over previous
//
#include <hip/hip_runtime.h>

// LSTM: S=4096, I=64, H=1024, O=1, fp32.
// Persistent cooperative kernel, 128 blocks x 512 threads (r6 skeleton).
// Round-9 change: weights live in REGISTERS during the step loop.
//   r2/r3 failed because global-sourced loads are rematerializable (and the
//   asm "+v" array pin forced scratch). ds_read-sourced values are NOT
//   remat-able (compiler can't prove LDS unchanged) -> RA must keep them in
//   VGPRs. So: stage weights global->LDS once, then copy each thread's 68
//   floats into 17 NAMED float4 registers before the loop. In-loop LDS
//   traffic drops from 139KB (weights) + h to h-reads only (~0.7us/step cut).
// Protocol (rounds 5-6, validated): tagged 8-byte slots {tag:32|h_bits:32},
// relaxed agent-scope atomics, tagged double buffer, zero fences, one
// __syncthreads per step, wave-0 gather + coalesced 64B line publish
// (WRITE_SIZE must stay 32768 KB).

#define SEQ_LEN 4096
#define HID 1024
#define NBLK 128
#define TPB 512
#define HPB 8      // h-indices per block (one per wave)

__device__ __forceinline__ float fast_sigmoid(float x) {
    return __builtin_amdgcn_rcpf(1.0f + __builtin_amdgcn_exp2f(-1.4426950408889634f * x));
}
__device__ __forceinline__ float fast_tanh(float x) {
    return fmaf(-2.0f, __builtin_amdgcn_rcpf(1.0f + __builtin_amdgcn_exp2f(2.8853900817779268f * x)), 1.0f);
}

// ws: unsigned long long slots[2][1024]. {tag<<32 | fp32 bits}. Zero-init:
// buffer0 tag0/val0 == h_0 = 0 (correct); buffer1 receives odd tags.
__global__ void lstm_init_kernel(unsigned long long* ws) {
    int t = threadIdx.x;
    #pragma unroll
    for (int k = 0; k < 8; ++k) ws[t + 256 * k] = 0ull;
}

__global__ __launch_bounds__(TPB, 1) void lstm_persistent_kernel(
    const float* __restrict__ input,   // [4096][64]
    const float* __restrict__ W_ih,    // [4096][64]
    const float* __restrict__ W_hh,    // [4096][1024]
    const float* __restrict__ b_ih,    // [4096]
    const float* __restrict__ b_hh,    // [4096]
    const float* __restrict__ W_lin,   // [1][1024]
    const float* __restrict__ b_lin,   // [1]
    float* __restrict__ out,           // [1]
    unsigned long long* __restrict__ ws)
{
    const int t   = threadIdx.x;
    const int b   = blockIdx.x;
    const int w   = t >> 6;      // wave in block (0..7)
    const int l   = t & 63;      // lane
    const int grp = l >> 4;      // gate q (i,f,g,o)
    const int sl  = l & 15;      // sub-lane within gate group
    const int j   = HPB * b + w; // owned h index
    const int row = grp * HID + j;

    unsigned long long* slot0 = ws;          // even tags
    unsigned long long* slot1 = ws + HID;    // odd tags

    __shared__ float4 wlds4[17 * TPB];       // 136 KB weight staging
    __shared__ float  hs[2][HID];            // double-buffered h (8 KB)
    __shared__ unsigned long long pub[HPB];  // tagged intra-block handoff
    __shared__ float  red[HPB];

    // ---- stage this block's 32 gate-rows into LDS ----
    {
        const float4* Whh4 = (const float4*)(W_hh + (size_t)row * HID);
        #pragma unroll
        for (int c = 0; c < 16; ++c)
            wlds4[c * TPB + t] = Whh4[sl + 16 * c];     // W_hh[row][64c+4sl..+3]
        wlds4[16 * TPB + t] = ((const float4*)(W_ih + (size_t)row * 64))[sl];
    }
    float bias[4];
    #pragma unroll
    for (int q = 0; q < 4; ++q) bias[q] = b_ih[q * HID + j] + b_hh[q * HID + j];
    if (t < HPB) pub[t] = 0ull;
    __syncthreads();   // weights staged, pub initialized

    // ---- LDS -> named registers (NOT remat-able: RA must keep in VGPRs) ----
    const float4 W0  = wlds4[ 0 * TPB + t];
    const float4 W1  = wlds4[ 1 * TPB + t];
    const float4 W2  = wlds4[ 2 * TPB + t];
    const float4 W3  = wlds4[ 3 * TPB + t];
    const float4 W4  = wlds4[ 4 * TPB + t];
    const float4 W5  = wlds4[ 5 * TPB + t];
    const float4 W6  = wlds4[ 6 * TPB + t];
    const float4 W7  = wlds4[ 7 * TPB + t];
    const float4 W8  = wlds4[ 8 * TPB + t];
    const float4 W9  = wlds4[ 9 * TPB + t];
    const float4 W10 = wlds4[10 * TPB + t];
    const float4 W11 = wlds4[11 * TPB + t];
    const float4 W12 = wlds4[12 * TPB + t];
    const float4 W13 = wlds4[13 * TPB + t];
    const float4 W14 = wlds4[14 * TPB + t];
    const float4 W15 = wlds4[15 * TPB + t];
    const float4 W16 = wlds4[16 * TPB + t];   // W_ih fragment

    const float4* xin4 = (const float4*)input;
    float c_state = 0.0f;

    for (int s = 0; s < SEQ_LEN; ++s) {
        float4 x4 = xin4[s * 16 + sl];   // issue before poll (cacheable)

        // ---- poll 2 tagged slots (relaxed agent atomics, rd-flags) ----
        unsigned long long* rs = (s & 1) ? slot1 : slot0;
        const unsigned tag = (unsigned)s;
        unsigned long long v0, v1;
        bool r0 = false, r1 = false;
        do {
            if (!r0) { v0 = __hip_atomic_load(&rs[t      ], __ATOMIC_RELAXED, __HIP_MEMORY_SCOPE_AGENT);
                       r0 = ((unsigned)(v0 >> 32) == tag); }
            if (!r1) { v1 = __hip_atomic_load(&rs[t + 512], __ATOMIC_RELAXED, __HIP_MEMORY_SCOPE_AGENT);
                       r1 = ((unsigned)(v1 >> 32) == tag); }
        } while (!(r0 && r1));

        float* hsb = hs[s & 1];
        hsb[t      ] = __uint_as_float((unsigned)(v0 & 0xffffffffull));
        hsb[t + 512] = __uint_as_float((unsigned)(v1 & 0xffffffffull));

        __syncthreads();   // the ONE barrier per step: full h_s staged

        // ---- 68 FMAs: weights from REGISTERS, h broadcast-read from LDS ----
        const float4* hs4 = (const float4*)hsb;
        float a0 = 0.f, a1 = 0.f, a2 = 0.f, a3 = 0.f;
        #define FMA_CHUNK(Wc, c, acc) { float4 h4_ = hs4[16 * (c) + sl];      \
            acc = fmaf((Wc).x, h4_.x, acc); acc = fmaf((Wc).y, h4_.y, acc);   \
            acc = fmaf((Wc).z, h4_.z, acc); acc = fmaf((Wc).w, h4_.w, acc); }
        FMA_CHUNK(W0,  0, a0) FMA_CHUNK(W1,  1, a1)
        FMA_CHUNK(W2,  2, a2) FMA_CHUNK(W3,  3, a3)
        FMA_CHUNK(W4,  4, a0) FMA_CHUNK(W5,  5, a1)
        FMA_CHUNK(W6,  6, a2) FMA_CHUNK(W7,  7, a3)
        FMA_CHUNK(W8,  8, a0) FMA_CHUNK(W9,  9, a1)
        FMA_CHUNK(W10, 10, a2) FMA_CHUNK(W11, 11, a3)
        FMA_CHUNK(W12, 12, a0) FMA_CHUNK(W13, 13, a1)
        FMA_CHUNK(W14, 14, a2) FMA_CHUNK(W15, 15, a3)
        #undef FMA_CHUNK
        a0 = fmaf(W16.x, x4.x, a0); a1 = fmaf(W16.y, x4.y, a1);
        a2 = fmaf(W16.z, x4.z, a2); a3 = fmaf(W16.w, x4.w, a3);
        float acc = (a0 + a1) + (a2 + a3);

        // reduce across 16 lanes of the gate group
        acc += __shfl_xor(acc, 1);
        acc += __shfl_xor(acc, 2);
        acc += __shfl_xor(acc, 4);
        acc += __shfl_xor(acc, 8);

        float gi = __shfl(acc, 0)  + bias[0];
        float gf = __shfl(acc, 16) + bias[1];
        float gg = __shfl(acc, 32) + bias[2];
        float go = __shfl(acc, 48) + bias[3];

        float ig = fast_sigmoid(gi);
        float fg = fast_sigmoid(gf);
        float cg = fast_tanh(gg);
        float og = fast_sigmoid(go);
        c_state  = fmaf(fg, c_state, ig * cg);
        float hn = og * fast_tanh(c_state);

        // ---- intra-block handoff: wave w lane 0 posts tagged hn to LDS ----
        const unsigned ntag = (unsigned)(s + 1);
        if (l == 0) {
            unsigned long long pv = ((unsigned long long)ntag << 32) |
                                    (unsigned long long)__float_as_uint(hn);
            __hip_atomic_store(&pub[w], pv, __ATOMIC_RELAXED, __HIP_MEMORY_SCOPE_WORKGROUP);
        }
        // ---- wave 0 lanes 0..7 gather the 8 words, publish one 64B line ----
        if (w == 0 && l < HPB) {
            unsigned long long pv;
            do {
                pv = __hip_atomic_load(&pub[l], __ATOMIC_RELAXED, __HIP_MEMORY_SCOPE_WORKGROUP);
            } while ((unsigned)(pv >> 32) != ntag);
            unsigned long long* wsl = (s & 1) ? slot0 : slot1;   // buffer (s+1)&1
            __hip_atomic_store(&wsl[HPB * b + l], pv, __ATOMIC_RELAXED, __HIP_MEMORY_SCOPE_AGENT);
        }
        // no trailing barrier: hs double-buffered; slot-tag deps bound skew
    }

    // ---- final projection: h_4096 (tag 4096, even -> slot0) . W_lin + b_lin ----
    if (b == 0) {
        const unsigned tag = (unsigned)SEQ_LEN;
        unsigned long long v0, v1;
        bool r0 = false, r1 = false;
        do {
            if (!r0) { v0 = __hip_atomic_load(&slot0[t      ], __ATOMIC_RELAXED, __HIP_MEMORY_SCOPE_AGENT);
                       r0 = ((unsigned)(v0 >> 32) == tag); }
            if (!r1) { v1 = __hip_atomic_load(&slot0[t + 512], __ATOMIC_RELAXED, __HIP_MEMORY_SCOPE_AGENT);
                       r1 = ((unsigned)(v1 >> 32) == tag); }
        } while (!(r0 && r1));
        float p = __uint_as_float((unsigned)(v0 & 0xffffffffull)) * W_lin[t] +
                  __uint_as_float((unsigned)(v1 & 0xffffffffull)) * W_lin[t + 512];
        #pragma unroll
        for (int m = 32; m >= 1; m >>= 1) p += __shfl_xor(p, m);
        if (l == 0) red[w] = p;
        __syncthreads();
        if (t == 0) {
            float r = 0.f;
            #pragma unroll
            for (int k = 0; k < HPB; ++k) r += red[k];
            out[0] = r + b_lin[0];
        }
    }
}

extern "C" void kernel_launch(void* const* d_in, const int* in_sizes, int n_in,
                              void* d_out, int out_size, void* d_ws, size_t ws_size,
                              hipStream_t stream) {
    const float* input = (const float*)d_in[0];
    const float* W_ih  = (const float*)d_in[1];
    const float* W_hh  = (const float*)d_in[2];
    const float* b_ih  = (const float*)d_in[3];
    const float* b_hh  = (const float*)d_in[4];
    const float* W_lin = (const float*)d_in[5];
    const float* b_lin = (const float*)d_in[6];
    float* out = (float*)d_out;
    unsigned long long* ws = (unsigned long long*)d_ws;

    hipLaunchKernelGGL(lstm_init_kernel, dim3(1), dim3(256), 0, stream, ws);

    void* args[] = { (void*)&input, (void*)&W_ih, (void*)&W_hh, (void*)&b_ih,
                     (void*)&b_hh, (void*)&W_lin, (void*)&b_lin, (void*)&out, (void*)&ws };
    (void)hipLaunchCooperativeKernel((void*)lstm_persistent_kernel, dim3(NBLK), dim3(TPB),
                                     args, 0, stream);
}